// Round 15
// baseline (47.870 us; speedup 1.0000x reference)
//
#include <hip/hip_runtime.h>

typedef float f32x4 __attribute__((ext_vector_type(4)));

// B=4096 rows, NPTS=4097 points, M=4096 outputs per row.
constexpr int NPTS = 4097;
constexpr int M    = 4096;
constexpr int TPB  = 512;   // 8 waves -> 4 blocks/CU co-resident (VGPR<=64)
constexpr int NW   = TPB / 64;
constexpr int NJ   = 2;     // 2 groups of 4 elements per thread; NJ*TPB*4 == M
// thread owns elements e(j) = j*2048 + tid*4 .. +3 (lane-contiguous)

struct Lds {
    float wt[NW][NJ];     // per-wave scanned group totals
    float gram[NW][6];    // per-wave Gram/projection partials (+Sxx)
};

// 4-element trapezoid scan from two aligned f32x4 loads; S = row misalignment
// (compile-time -> pure register selects, no scratch).
template<int S>
__device__ __forceinline__ void scan4(const f32x4 a, const f32x4 c,
                                      const f32x4 tq, float tn,
                                      float (&xsj)[4], float (&zlj)[4], float& gsj)
{
    const float m[8] = {a.x, a.y, a.z, a.w, c.x, c.y, c.z, c.w};
    const float x0 = m[S+0], x1 = m[S+1], x2 = m[S+2], x3 = m[S+3], x4 = m[S+4];
    const float i0 = (0.5f * (tq.y - tq.x)) * (x0 + x1);
    const float i1 = (0.5f * (tq.z - tq.y)) * (x1 + x2);
    const float i2 = (0.5f * (tq.w - tq.z)) * (x2 + x3);
    const float i3 = (0.5f * (tn   - tq.w)) * (x3 + x4);
    zlj[0] = i0;
    zlj[1] = i0 + i1;
    zlj[2] = zlj[1] + i2;
    zlj[3] = zlj[2] + i3;
    gsj = zlj[3];
    xsj[0] = x1; xsj[1] = x2; xsj[2] = x3; xsj[3] = x4;
}

template<int S, bool RHALF>
__device__ __forceinline__ void body(const float* __restrict__ x,
                                     const float* __restrict__ t,
                                     float r, float ny,
                                     float* __restrict__ out,
                                     int b, int B, Lds& L)
{
    const int tid  = threadIdx.x;
    const int lane = tid & 63;
    const int wid  = tid >> 6;

    // x row base = b*4097 floats; b*4097 ≡ b (mod 4) -> (xrow - S), S=b&3, is
    // 16B-aligned. Row b=4095 (S=3) reads end exactly at x's last element;
    // S<3 rows over-read <=3 floats into the next row (in bounds).
    const float* __restrict__ xal = x + (size_t)b * NPTS - S;

    float xs[NJ][4];   // x_sl = x[m+1]
    float zl[NJ][4];   // local scan, later z
    float gs[NJ];      // group sums

#pragma unroll
    for (int j = 0; j < NJ; ++j) {
        const int e = j * 2048 + tid * 4;
        const f32x4 a4 = *(const f32x4*)(xal + e);
        const f32x4 c4 = *(const f32x4*)(xal + e + 4);
        const f32x4 tq = *(const f32x4*)(t + e);       // aligned, L2-hot
        const float tn = t[e + 4];                     // coalesced, L2-hot
        scan4<S>(a4, c4, tq, tn, xs[j], zl[j], gs[j]);
    }

    // ---- 2 simultaneous wave inclusive scans of group sums ----
    float sc[NJ];
#pragma unroll
    for (int c = 0; c < NJ; ++c) sc[c] = gs[c];
#pragma unroll
    for (int d = 1; d < 64; d <<= 1) {
#pragma unroll
        for (int c = 0; c < NJ; ++c) {
            float u = __shfl_up(sc[c], d, 64);
            if (lane >= d) sc[c] += u;
        }
    }
    if (lane == 63) {
#pragma unroll
        for (int c = 0; c < NJ; ++c) L.wt[wid][c] = sc[c];
    }
    __syncthreads();

    float woff[NJ] = {}, Tt[NJ] = {};
#pragma unroll
    for (int w = 0; w < NW; ++w) {
#pragma unroll
        for (int c = 0; c < NJ; ++c) {
            const float v = L.wt[w][c];   // wave-uniform addr -> LDS broadcast
            Tt[c] += v;
            if (w < wid) woff[c] += v;
        }
    }
    // exclusive prefix per group; memory order = j-major, wave, lane
    {
        float jacc = ny;
#pragma unroll
        for (int j = 0; j < NJ; ++j) {
            const float zb = jacc + woff[j] + (sc[j] - gs[j]);
            jacc += Tt[j];
#pragma unroll
            for (int i = 0; i < 4; ++i) zl[j][i] = zb + zl[j][i];
        }
    }

    // ---- z, w=z^r, Gram/projection sums in f32 (group-pairwise), + Sxx ----
    float s0 = 0, s1 = 0, s2 = 0, s3 = 0, s4 = 0, s5 = 0;
#pragma unroll
    for (int j = 0; j < NJ; ++j) {
        float pzz = 0, pzw = 0, pww = 0, pxz = 0, pxw = 0, pxx = 0;
#pragma unroll
        for (int i = 0; i < 4; ++i) {
            const float z  = zl[j][i];
            const float w  = RHALF ? sqrtf(z) : powf(z, r);
            const float xv = xs[j][i];
            pzz = fmaf(z,  z,  pzz);
            pzw = fmaf(z,  w,  pzw);
            pww = fmaf(w,  w,  pww);
            pxz = fmaf(xv, z,  pxz);
            pxw = fmaf(xv, w,  pxw);
            pxx = fmaf(xv, xv, pxx);
        }
        s0 += pzz; s1 += pzw; s2 += pww; s3 += pxz; s4 += pxw; s5 += pxx;
    }
#pragma unroll
    for (int d = 32; d > 0; d >>= 1) {
        s0 += __shfl_down(s0, d, 64);
        s1 += __shfl_down(s1, d, 64);
        s2 += __shfl_down(s2, d, 64);
        s3 += __shfl_down(s3, d, 64);
        s4 += __shfl_down(s4, d, 64);
        s5 += __shfl_down(s5, d, 64);
    }
    if (lane == 0) {
        L.gram[wid][0] = s0; L.gram[wid][1] = s1; L.gram[wid][2] = s2;
        L.gram[wid][3] = s3; L.gram[wid][4] = s4; L.gram[wid][5] = s5;
    }
    __syncthreads();

    // ---- 2x2 normal-equations solve (f64, redundant per-thread; LDS
    //      broadcast reads). r2 via LS identity (validated R10). ----
    double a0 = 0, a1 = 0, a2 = 0, a3 = 0, a4 = 0, a5 = 0;
#pragma unroll
    for (int w = 0; w < NW; ++w) {
        a0 += L.gram[w][0]; a1 += L.gram[w][1]; a2 += L.gram[w][2];
        a3 += L.gram[w][3]; a4 += L.gram[w][4]; a5 += L.gram[w][5];
    }
    const double det = a0 * a2 - a1 * a1;
    const double inv = 1.0 / det;
    const double c0d = (a3 * a2 - a4 * a1) * inv;
    const double c1d = (a4 * a0 - a3 * a1) * inv;
    const float c0 = (float)c0d;
    const float c1 = (float)c1d;
    if (tid == 0) {
        out[(size_t)b * 2 + 0] = c0;
        out[(size_t)b * 2 + 1] = c1;
        out[(size_t)B * 2 + 2 * (size_t)B * M + b] =
            (float)(a5 - c0d * a3 - c1d * a4);
    }

    // ---- x_hat, res (regular coalesced f32x4 stores) ----
    float* __restrict__ xhat = out + (size_t)B * 2 + (size_t)b * M;
    float* __restrict__ res  = xhat + (size_t)B * M;

#pragma unroll
    for (int j = 0; j < NJ; ++j) {
        const int e = j * 2048 + tid * 4;
        f32x4 hv, rv;
#pragma unroll
        for (int i = 0; i < 4; ++i) {
            const float z = zl[j][i];
            const float w = RHALF ? sqrtf(z) : powf(z, r);
            const float h = c0 * z + c1 * w;
            hv[i] = h;
            rv[i] = xs[j][i] - h;
        }
        *(f32x4*)(xhat + e) = hv;
        *(f32x4*)(res  + e) = rv;
    }
}

__global__ __launch_bounds__(TPB)
void vp_kernel(const float* __restrict__ x, const float* __restrict__ t,
               const float* __restrict__ params, float* __restrict__ out, int B)
{
    __shared__ Lds L;
    const float r  = params[0];
    const float ny = params[1];
    const int  b   = blockIdx.x;

    if (r == 0.5f) {
        switch (b & 3) {
        case 0:  body<0, true>(x, t, r, ny, out, b, B, L); break;
        case 1:  body<1, true>(x, t, r, ny, out, b, B, L); break;
        case 2:  body<2, true>(x, t, r, ny, out, b, B, L); break;
        default: body<3, true>(x, t, r, ny, out, b, B, L); break;
        }
    } else {
        switch (b & 3) {
        case 0:  body<0, false>(x, t, r, ny, out, b, B, L); break;
        case 1:  body<1, false>(x, t, r, ny, out, b, B, L); break;
        case 2:  body<2, false>(x, t, r, ny, out, b, B, L); break;
        default: body<3, false>(x, t, r, ny, out, b, B, L); break;
        }
    }
}

extern "C" void kernel_launch(void* const* d_in, const int* in_sizes, int n_in,
                              void* d_out, int out_size, void* d_ws, size_t ws_size,
                              hipStream_t stream) {
    const float* x = (const float*)d_in[0];
    const float* t = (const float*)d_in[1];
    const float* p = (const float*)d_in[2];
    float* out     = (float*)d_out;
    const int B    = in_sizes[0] / NPTS;   // 4096

    vp_kernel<<<dim3(B), dim3(TPB), 0, stream>>>(x, t, p, out, B);
}

// Round 16
// 44.479 us; speedup vs baseline: 1.0762x; 1.0762x over previous
//
#include <hip/hip_runtime.h>

typedef float f32x4 __attribute__((ext_vector_type(4)));

// B=4096 rows, NPTS=4097 points, M=4096 outputs per row.
constexpr int NPTS = 4097;
constexpr int M    = 4096;
constexpr int TPB  = 256;   // 4 waves (best-known structure, R8/R10)
constexpr int NW   = TPB / 64;
constexpr int NJ   = 4;     // 4 groups of 4 elements per thread; NJ*TPB*4 == M
// thread owns elements e(j) = j*1024 + tid*4 .. +3 (lane-contiguous)

struct Lds {
    float wt[NW][NJ];     // per-wave scanned group totals
    float gram[NW][6];    // per-wave Gram/projection partials (+Sxx)
};

// ---- setup: d[m] = 0.5*(t[m+1]-t[m]), m = 0..M-1 (one-time per launch) ----
__global__ __launch_bounds__(256)
void k_dtab(const float* __restrict__ t, float* __restrict__ d)
{
    const int i = blockIdx.x * 256 + threadIdx.x;
    if (i < M) d[i] = 0.5f * (t[i + 1] - t[i]);
}

// 4-element trapezoid scan; S = row misalignment (compile-time selects).
template<int S>
__device__ __forceinline__ void scan4(const f32x4 a, const f32x4 c,
                                      const f32x4 d4,
                                      float (&xsj)[4], float (&zlj)[4], float& gsj)
{
    const float m[8] = {a.x, a.y, a.z, a.w, c.x, c.y, c.z, c.w};
    const float x0 = m[S+0], x1 = m[S+1], x2 = m[S+2], x3 = m[S+3], x4 = m[S+4];
    const float i0 = d4.x * (x0 + x1);
    const float i1 = d4.y * (x1 + x2);
    const float i2 = d4.z * (x2 + x3);
    const float i3 = d4.w * (x3 + x4);
    zlj[0] = i0;
    zlj[1] = i0 + i1;
    zlj[2] = zlj[1] + i2;
    zlj[3] = zlj[2] + i3;
    gsj = zlj[3];
    xsj[0] = x1; xsj[1] = x2; xsj[2] = x3; xsj[3] = x4;
}

template<int S, bool RHALF>
__device__ __forceinline__ void body(const float* __restrict__ x,
                                     const float* __restrict__ dt2,
                                     float r, float ny,
                                     float* __restrict__ out,
                                     int b, int B, Lds& L)
{
    const int tid  = threadIdx.x;
    const int lane = tid & 63;
    const int wid  = tid >> 6;

    // x row base = b*4097 floats; b*4097 ≡ b (mod 4) -> (xrow - S), S=b&3, is
    // 16B-aligned. Row b=4095 (S=3) reads end exactly at x's last element;
    // S<3 rows over-read <=3 floats into the next row (in bounds).
    const float* __restrict__ xal = x + (size_t)b * NPTS - S;

    // ---- load burst first: all raw vectors in flight before any math ----
    f32x4 a4[NJ], c4[NJ], d4[NJ];
#pragma unroll
    for (int j = 0; j < NJ; ++j) {
        const int e = j * 1024 + tid * 4;
        a4[j] = *(const f32x4*)(xal + e);
        c4[j] = *(const f32x4*)(xal + e + 4);
        d4[j] = *(const f32x4*)(dt2 + e);     // precomputed half-dt, L2-hot
    }

    float xs[NJ][4];   // x_sl = x[m+1]
    float zl[NJ][4];   // local scan, later z
    float gs[NJ];      // group sums
#pragma unroll
    for (int j = 0; j < NJ; ++j)
        scan4<S>(a4[j], c4[j], d4[j], xs[j], zl[j], gs[j]);

    // ---- 4 simultaneous wave inclusive scans of group sums ----
    float sc[NJ];
#pragma unroll
    for (int c = 0; c < NJ; ++c) sc[c] = gs[c];
#pragma unroll
    for (int d = 1; d < 64; d <<= 1) {
#pragma unroll
        for (int c = 0; c < NJ; ++c) {
            float u = __shfl_up(sc[c], d, 64);
            if (lane >= d) sc[c] += u;
        }
    }
    if (lane == 63) {
#pragma unroll
        for (int c = 0; c < NJ; ++c) L.wt[wid][c] = sc[c];
    }
    __syncthreads();

    float woff[NJ] = {}, Tt[NJ] = {};
#pragma unroll
    for (int w = 0; w < NW; ++w) {
#pragma unroll
        for (int c = 0; c < NJ; ++c) {
            const float v = L.wt[w][c];
            Tt[c] += v;
            if (w < wid) woff[c] += v;
        }
    }
    // exclusive prefix per group; memory order = j-major, wave, lane
    {
        float jacc = ny;
#pragma unroll
        for (int j = 0; j < NJ; ++j) {
            const float zb = jacc + woff[j] + (sc[j] - gs[j]);
            jacc += Tt[j];
#pragma unroll
            for (int i = 0; i < 4; ++i) zl[j][i] = zb + zl[j][i];
        }
    }

    // ---- z, w=z^r, Gram/projection sums in f32 (group-pairwise), + Sxx ----
    float s0 = 0, s1 = 0, s2 = 0, s3 = 0, s4 = 0, s5 = 0;
#pragma unroll
    for (int j = 0; j < NJ; ++j) {
        float pzz = 0, pzw = 0, pww = 0, pxz = 0, pxw = 0, pxx = 0;
#pragma unroll
        for (int i = 0; i < 4; ++i) {
            const float z  = zl[j][i];
            const float w  = RHALF ? sqrtf(z) : powf(z, r);
            const float xv = xs[j][i];
            pzz = fmaf(z,  z,  pzz);
            pzw = fmaf(z,  w,  pzw);
            pww = fmaf(w,  w,  pww);
            pxz = fmaf(xv, z,  pxz);
            pxw = fmaf(xv, w,  pxw);
            pxx = fmaf(xv, xv, pxx);
        }
        s0 += pzz; s1 += pzw; s2 += pww; s3 += pxz; s4 += pxw; s5 += pxx;
    }
#pragma unroll
    for (int d = 32; d > 0; d >>= 1) {
        s0 += __shfl_down(s0, d, 64);
        s1 += __shfl_down(s1, d, 64);
        s2 += __shfl_down(s2, d, 64);
        s3 += __shfl_down(s3, d, 64);
        s4 += __shfl_down(s4, d, 64);
        s5 += __shfl_down(s5, d, 64);
    }
    if (lane == 0) {
        L.gram[wid][0] = s0; L.gram[wid][1] = s1; L.gram[wid][2] = s2;
        L.gram[wid][3] = s3; L.gram[wid][4] = s4; L.gram[wid][5] = s5;
    }
    __syncthreads();

    // ---- 2x2 normal-equations solve (f64, redundant per-thread; LDS
    //      broadcast reads). r2 via LS identity (validated R10). ----
    double a0 = 0, a1 = 0, a2 = 0, a3 = 0, a4d = 0, a5 = 0;
#pragma unroll
    for (int w = 0; w < NW; ++w) {
        a0 += L.gram[w][0]; a1  += L.gram[w][1]; a2 += L.gram[w][2];
        a3 += L.gram[w][3]; a4d += L.gram[w][4]; a5 += L.gram[w][5];
    }
    const double det = a0 * a2 - a1 * a1;
    const double inv = 1.0 / det;
    const double c0d = (a3 * a2 - a4d * a1) * inv;
    const double c1d = (a4d * a0 - a3 * a1) * inv;
    const float c0 = (float)c0d;
    const float c1 = (float)c1d;
    if (tid == 0) {
        out[(size_t)b * 2 + 0] = c0;
        out[(size_t)b * 2 + 1] = c1;
        out[(size_t)B * 2 + 2 * (size_t)B * M + b] =
            (float)(a5 - c0d * a3 - c1d * a4d);
    }

    // ---- x_hat, res (regular coalesced f32x4 stores) ----
    float* __restrict__ xhat = out + (size_t)B * 2 + (size_t)b * M;
    float* __restrict__ res  = xhat + (size_t)B * M;

#pragma unroll
    for (int j = 0; j < NJ; ++j) {
        const int e = j * 1024 + tid * 4;
        f32x4 hv, rv;
#pragma unroll
        for (int i = 0; i < 4; ++i) {
            const float z = zl[j][i];
            const float w = RHALF ? sqrtf(z) : powf(z, r);
            const float h = c0 * z + c1 * w;
            hv[i] = h;
            rv[i] = xs[j][i] - h;
        }
        *(f32x4*)(xhat + e) = hv;
        *(f32x4*)(res  + e) = rv;
    }
}

__global__ __launch_bounds__(TPB)
void vp_kernel(const float* __restrict__ x, const float* __restrict__ dt2,
               const float* __restrict__ params, float* __restrict__ out, int B)
{
    __shared__ Lds L;
    const float r  = params[0];
    const float ny = params[1];
    const int  b   = blockIdx.x;

    if (r == 0.5f) {
        switch (b & 3) {
        case 0:  body<0, true>(x, dt2, r, ny, out, b, B, L); break;
        case 1:  body<1, true>(x, dt2, r, ny, out, b, B, L); break;
        case 2:  body<2, true>(x, dt2, r, ny, out, b, B, L); break;
        default: body<3, true>(x, dt2, r, ny, out, b, B, L); break;
        }
    } else {
        switch (b & 3) {
        case 0:  body<0, false>(x, dt2, r, ny, out, b, B, L); break;
        case 1:  body<1, false>(x, dt2, r, ny, out, b, B, L); break;
        case 2:  body<2, false>(x, dt2, r, ny, out, b, B, L); break;
        default: body<3, false>(x, dt2, r, ny, out, b, B, L); break;
        }
    }
}

extern "C" void kernel_launch(void* const* d_in, const int* in_sizes, int n_in,
                              void* d_out, int out_size, void* d_ws, size_t ws_size,
                              hipStream_t stream) {
    const float* x = (const float*)d_in[0];
    const float* t = (const float*)d_in[1];
    const float* p = (const float*)d_in[2];
    float* out     = (float*)d_out;
    float* dt2     = (float*)d_ws;          // 4096 floats of half-dt
    const int B    = in_sizes[0] / NPTS;    // 4096

    k_dtab<<<dim3((M + 255) / 256), dim3(256), 0, stream>>>(t, dt2);
    vp_kernel<<<dim3(B), dim3(TPB), 0, stream>>>(x, dt2, p, out, B);
}